// Round 3
// baseline (100.835 us; speedup 1.0000x reference)
//
#include <hip/hip_runtime.h>
#include <hip/hip_bf16.h>
#include <stdint.h>

// Problem constants: B=4, L=2048, D=1024, vocab<32, N_GRAM=3
#define LSEQ 2048
#define DDIM 1024

typedef __attribute__((ext_vector_type(8))) short bf16x8;
typedef __attribute__((ext_vector_type(16))) float f32x16;

__device__ __forceinline__ ushort f2bf(float x) {
    uint32_t u = __builtin_bit_cast(uint32_t, x);
    u += 0x7fffu + ((u >> 16) & 1u);   // RNE (inputs finite/normal)
    return (ushort)(u >> 16);
}

__device__ __forceinline__ void stage16(const void* g, void* lds) {
    __builtin_amdgcn_global_load_lds((const __attribute__((address_space(1))) void*)g,
                                     (__attribute__((address_space(3))) void*)lds, 16, 0, 0);
}

// Swizzled byte offset in a row-major bf16 buffer with 2048B row stride.
// Within each 128B (64-element) k-block, the 16B slot index is XORed with (row&7).
// Rule 21: this permutation is BAKED into the buffer by the producer kernels, so
// global_load_lds staging copies linearly; the ds_read side applies the same XOR.
__device__ __forceinline__ int swz_off(int row, int k) {
    return row * 2048 + ((k >> 6) << 7) + ((((k >> 3) & 7) ^ (row & 7)) << 4) + ((k & 7) << 1);
}

// ---------------- Kernel 1: pack trailing 3-gram into a 15-bit key ----------------
__global__ void keys_kernel(const int* __restrict__ ids, int* __restrict__ keys, int total) {
    int idx = blockIdx.x * 256 + threadIdx.x;
    if (idx >= total) return;
    int i = idx & (LSEQ - 1);
    int k = 0;
    if (i >= 2) k = (ids[idx - 2] << 10) | (ids[idx - 1] << 5) | ids[idx];
    keys[idx] = k;  // i<2 -> padded zero 3-gram -> key 0 (matches reference pad semantics)
}

// ---------------- Kernel 2: pooled[b,i,:] = mean_{j<i, key[j]==key[i]} H[b,j,:] ----
// Deterministic LDS-bitmap match collection; bf16 output, swizzle-baked layout.
__global__ __launch_bounds__(256) void pooled_kernel(const float4* __restrict__ H4,
                                                     const int* __restrict__ keys,
                                                     char* __restrict__ Pb) {
    int row = blockIdx.x;            // b*L + i
    int i = row & (LSEQ - 1);
    int base = row - i;              // b*L
    int tid = threadIdx.x;
    int key_i = keys[row];

    __shared__ unsigned bm[8];
    float4 acc = make_float4(0.f, 0.f, 0.f, 0.f);
    int count = 0;

    for (int j0 = 0; j0 < i; j0 += 256) {
        if (tid < 8) bm[tid] = 0u;
        __syncthreads();
        int j = j0 + tid;
        if (j < i && keys[base + j] == key_i)
            atomicOr(&bm[tid >> 5], 1u << (tid & 31));
        __syncthreads();
        #pragma unroll
        for (int w = 0; w < 8; ++w) {
            unsigned m = bm[w];
            while (m) {
                int bit = __ffs(m) - 1;
                m &= m - 1;
                int j2 = j0 + w * 32 + bit;
                count++;
                float4 h = H4[(size_t)(base + j2) * (DDIM / 4) + tid];
                acc.x += h.x; acc.y += h.y; acc.z += h.z; acc.w += h.w;
            }
        }
        __syncthreads();
    }
    float s = 1.0f / (float)(count > 0 ? count : 1);
    ushort4 o;
    o.x = f2bf(acc.x * s); o.y = f2bf(acc.y * s);
    o.z = f2bf(acc.z * s); o.w = f2bf(acc.w * s);
    *(ushort4*)(Pb + swz_off(row, tid * 4)) = o;   // (k&7) in {0,4} -> 8B aligned
}

// ---------------- Kernel 3: W[K][N] fp32 -> Wt[N][K] bf16, swizzle-baked ----------
__global__ __launch_bounds__(256) void transpose_w(const float* __restrict__ W1,
                                                   const float* __restrict__ W2,
                                                   char* __restrict__ W1t,
                                                   char* __restrict__ W2t) {
    const float* W = blockIdx.z ? W2 : W1;
    char* Wt = blockIdx.z ? W2t : W1t;
    __shared__ ushort t[64][65];
    int k0 = blockIdx.x * 64, n0 = blockIdx.y * 64;
    int tid = threadIdx.x;
    #pragma unroll
    for (int it = 0; it < 16; ++it) {
        int idx = it * 256 + tid;
        int r = idx >> 6, c = idx & 63;
        t[c][r] = f2bf(W[(size_t)(k0 + r) * DDIM + n0 + c]);
    }
    __syncthreads();
    #pragma unroll
    for (int it = 0; it < 16; ++it) {
        int idx = it * 256 + tid;
        int r = idx >> 6, c = idx & 63;
        *(ushort*)(Wt + swz_off(n0 + r, k0 + c)) = t[r][c];
    }
}

// ---------------- Kernel 4: out = H@W1 + P@W2 + (b1+b2), 32x32x16 bf16 MFMA -------
// 128x128 tile, BK=64, 4 waves (2x2), wave tile 64x64 = 2x2 frags of 32x32.
// Double-buffered LDS, 2-phase pipeline: stage(t+1) issued before compute(t);
// single counted-drain (vmcnt0+lgkm0) + raw s_barrier per K-step.
// H path (k-tiles 0..15): A staged via reg fp32->bf16 convert + swizzled ds_write
// (T14 issue-early / write-late). P path (16..31): all global_load_lds.
__global__ __launch_bounds__(256, 2) void gemm_bf16(
    const float* __restrict__ H,      // [8192][1024] fp32
    const char* __restrict__ Pb,      // [8192][1024] bf16, swizzle-baked
    const char* __restrict__ W1t,     // [1024 n][1024 k] bf16, swizzle-baked
    const char* __restrict__ W2t,
    const float* __restrict__ b1,
    const float* __restrict__ b2,
    float* __restrict__ out)          // [8192][1024] fp32
{
    __shared__ __align__(128) char As[2][16384];   // [128 rows][128B (64 bf16)]
    __shared__ __align__(128) char Bs[2][16384];

    const int tid = threadIdx.x;
    const int lane = tid & 63;
    const int wid = tid >> 6;
    const int wr = wid >> 1, wc = wid & 1;
    const int l31 = lane & 31;
    const int hi2 = lane >> 5;
    const int x7 = l31 & 7;

    const int row0 = blockIdx.x * 128;
    const int col0 = blockIdx.y * 128;

    f32x16 acc[2][2];
    #pragma unroll
    for (int mm = 0; mm < 2; ++mm)
        #pragma unroll
        for (int nn = 0; nn < 2; ++nn)
            #pragma unroll
            for (int q = 0; q < 16; ++q) acc[mm][nn][q] = 0.f;

    // staging geometry: one 4KB issue covers 32 rows; lane's 16B at
    // o = i*4096 + wid*1024 + lane*16 -> row = i*32 + sr, in-row byte = sb
    const int sr = wid * 8 + (lane >> 3);
    const int sb = (lane & 7) * 16;

    // H reg-stage geometry: thread owns row (tid>>1), 64B half (tid&1) of the 128B LDS row
    const int hrow = tid >> 1;
    const int hhalf = tid & 1;
    const float* Hrow = H + (size_t)(row0 + hrow) * DDIM + hhalf * 32;
    const int hx = hrow & 7;

    // frag read row bases
    const int ra = wr * 64 + l31;
    const int rb = wc * 64 + l31;

    auto stageB = [&](int bi, const char* SB, int kb) {
        #pragma unroll
        for (int i = 0; i < 4; ++i)
            stage16(SB + (size_t)(col0 + i * 32 + sr) * 2048 + kb + sb,
                    &Bs[bi][i * 4096 + wid * 1024]);
    };
    auto stageA_pb = [&](int bi, int kb) {
        #pragma unroll
        for (int i = 0; i < 4; ++i)
            stage16(Pb + (size_t)(row0 + i * 32 + sr) * 2048 + kb + sb,
                    &As[bi][i * 4096 + wid * 1024]);
    };
    auto writeH = [&](int bi, const float4* hv) {
        #pragma unroll
        for (int j = 0; j < 4; ++j) {
            union { ushort u[8]; int4 v; } p;
            float4 a = hv[2 * j], b = hv[2 * j + 1];
            p.u[0] = f2bf(a.x); p.u[1] = f2bf(a.y); p.u[2] = f2bf(a.z); p.u[3] = f2bf(a.w);
            p.u[4] = f2bf(b.x); p.u[5] = f2bf(b.y); p.u[6] = f2bf(b.z); p.u[7] = f2bf(b.w);
            int slot = (hhalf * 4 + j) ^ hx;                 // bake swizzle at write
            *(int4*)&As[bi][hrow * 128 + slot * 16] = p.v;   // ds_write_b128, conflict-free
        }
    };

    // ---- prologue: stage k-tile 0 (H path) into buffer 0 ----
    stageB(0, W1t, 0);
    {
        float4 hv0[8];
        #pragma unroll
        for (int j = 0; j < 8; ++j) hv0[j] = *(const float4*)(Hrow + j * 4);
        writeH(0, hv0);
    }
    asm volatile("s_waitcnt vmcnt(0) lgkmcnt(0)" ::: "memory");
    __builtin_amdgcn_s_barrier();

    int cur = 0;
    #pragma unroll 1
    for (int t = 0; t < 32; ++t) {
        const int t1 = t + 1;
        float4 hv[8];
        if (t1 < 16) {                       // prefetch H k-tile t1 into regs (write-late)
            stageB(cur ^ 1, W1t, t1 << 7);
            const float* hs = Hrow + t1 * 64;
            #pragma unroll
            for (int j = 0; j < 8; ++j) hv[j] = *(const float4*)(hs + j * 4);
        } else if (t1 < 32) {                // P path: pure global_load_lds
            stageB(cur ^ 1, W2t, (t1 & 15) << 7);
            stageA_pb(cur ^ 1, (t1 & 15) << 7);
        }

        // fragment reads from buf[cur]; XOR-swizzled slot -> conflict-free
        bf16x8 af[2][4], bf[2][4];
        #pragma unroll
        for (int mm = 0; mm < 2; ++mm)
            #pragma unroll
            for (int ks = 0; ks < 4; ++ks)
                af[mm][ks] = *(const bf16x8*)&As[cur][(ra + mm * 32) * 128 +
                                                     (((ks * 2 + hi2) ^ x7) << 4)];
        #pragma unroll
        for (int nn = 0; nn < 2; ++nn)
            #pragma unroll
            for (int ks = 0; ks < 4; ++ks)
                bf[nn][ks] = *(const bf16x8*)&Bs[cur][(rb + nn * 32) * 128 +
                                                      (((ks * 2 + hi2) ^ x7) << 4)];

        #pragma unroll
        for (int ks = 0; ks < 4; ++ks)
            #pragma unroll
            for (int mm = 0; mm < 2; ++mm)
                #pragma unroll
                for (int nn = 0; nn < 2; ++nn)
                    acc[mm][nn] = __builtin_amdgcn_mfma_f32_32x32x16_bf16(
                        af[mm][ks], bf[nn][ks], acc[mm][nn], 0, 0, 0);

        if (t1 < 16) writeH(cur ^ 1, hv);    // convert + swizzled ds_write after MFMA

        asm volatile("s_waitcnt vmcnt(0) lgkmcnt(0)" ::: "memory");
        __builtin_amdgcn_s_barrier();
        cur ^= 1;
    }

    // epilogue: 32x32 C/D layout col=lane&31, row=(reg&3)+8*(reg>>2)+4*(lane>>5)
    #pragma unroll
    for (int mm = 0; mm < 2; ++mm) {
        #pragma unroll
        for (int nn = 0; nn < 2; ++nn) {
            const int c = col0 + wc * 64 + nn * 32 + l31;
            const float bias = b1[c] + b2[c];
            const int rbase = row0 + wr * 64 + mm * 32 + hi2 * 4;
            #pragma unroll
            for (int reg = 0; reg < 16; ++reg) {
                int r = rbase + (reg & 3) + 8 * (reg >> 2);
                out[(size_t)r * DDIM + c] = acc[mm][nn][reg] + bias;
            }
        }
    }
}

extern "C" void kernel_launch(void* const* d_in, const int* in_sizes, int n_in,
                              void* d_out, int out_size, void* d_ws, size_t ws_size,
                              hipStream_t stream) {
    const float* H  = (const float*)d_in[0];
    const int*   ids = (const int*)d_in[1];
    const float* W1 = (const float*)d_in[2];
    const float* b1 = (const float*)d_in[3];
    const float* W2 = (const float*)d_in[4];
    const float* b2 = (const float*)d_in[5];
    float* out = (float*)d_out;

    const int BL = in_sizes[1];      // B*L = 8192

    char* ws = (char*)d_ws;
    int* keys = (int*)ws;                            // 32KB used (64KB reserved)
    char* Pb  = ws + (64 << 10);                     // 16MB bf16 pooled (swizzled)
    char* W1t = ws + (64 << 10) + (16 << 20);        // 2MB
    char* W2t = ws + (64 << 10) + (18 << 20);        // 2MB
    // total ~20.06MB < proven-available 33.6MB

    keys_kernel<<<(BL + 255) / 256, 256, 0, stream>>>(ids, keys, BL);
    pooled_kernel<<<BL, 256, 0, stream>>>((const float4*)H, keys, Pb);
    transpose_w<<<dim3(16, 16, 2), 256, 0, stream>>>(W1, W2, W1t, W2t);
    gemm_bf16<<<dim3(BL / 128, DDIM / 128), 256, 0, stream>>>(H, Pb, W1t, W2t, b1, b2, out);
}

// Round 4
// 98.703 us; speedup vs baseline: 1.0216x; 1.0216x over previous
//
#include <hip/hip_runtime.h>
#include <hip/hip_bf16.h>
#include <stdint.h>

// Problem constants: B=4, L=2048, D=1024, vocab<32, N_GRAM=3
#define LSEQ 2048
#define DDIM 1024

typedef __attribute__((ext_vector_type(8))) short bf16x8;
typedef __attribute__((ext_vector_type(16))) float f32x16;

__device__ __forceinline__ ushort f2bf(float x) {
    uint32_t u = __builtin_bit_cast(uint32_t, x);
    u += 0x7fffu + ((u >> 16) & 1u);   // RNE (inputs finite/normal)
    return (ushort)(u >> 16);
}

__device__ __forceinline__ void stage16(const void* g, void* lds) {
    __builtin_amdgcn_global_load_lds((const __attribute__((address_space(1))) void*)g,
                                     (__attribute__((address_space(3))) void*)lds, 16, 0, 0);
}

// Swizzled byte offset in a row-major bf16 buffer, 2048B row stride.
// Within each 128B k-block, 16B slot index XORed with (row&7). Baked into global
// layout by producers (rule 21) so global_load_lds copies linearly; readers XOR.
__device__ __forceinline__ int swz_off(int row, int k) {
    return row * 2048 + ((k >> 6) << 7) + ((((k >> 3) & 7) ^ (row & 7)) << 4) + ((k & 7) << 1);
}

__device__ __forceinline__ int key_at(const int* __restrict__ ids, int base, int j) {
    return j >= 2 ? ((ids[base + j - 2] << 10) | (ids[base + j - 1] << 5) | ids[base + j]) : 0;
}

// ---------------- Kernel 1 (fused prep): pooled (blocks 0..8191) + W-transpose ----
__global__ __launch_bounds__(256) void prep(const float* __restrict__ H,
                                            const int* __restrict__ ids,
                                            const float* __restrict__ W1,
                                            const float* __restrict__ W2,
                                            char* __restrict__ Pb,
                                            char* __restrict__ W1t,
                                            char* __restrict__ W2t) {
    int bid = blockIdx.x;
    int tid = threadIdx.x;
    if (bid < 8192) {
        // pooled[b,i,:] = mean_{j<i, ngram match} H[b,j,:]; deterministic bitmap scan
        int row = bid;
        int i = row & (LSEQ - 1);
        int base = row - i;
        int key_i = key_at(ids, base, i);
        const float4* H4 = (const float4*)H;

        __shared__ unsigned bm[8];
        float4 acc = make_float4(0.f, 0.f, 0.f, 0.f);
        int count = 0;
        for (int j0 = 0; j0 < i; j0 += 256) {
            if (tid < 8) bm[tid] = 0u;
            __syncthreads();
            int j = j0 + tid;
            if (j < i && key_at(ids, base, j) == key_i)
                atomicOr(&bm[tid >> 5], 1u << (tid & 31));
            __syncthreads();
            #pragma unroll
            for (int w = 0; w < 8; ++w) {
                unsigned m = bm[w];
                while (m) {
                    int bit = __ffs(m) - 1;
                    m &= m - 1;
                    int j2 = j0 + w * 32 + bit;
                    count++;
                    float4 h = H4[(size_t)(base + j2) * (DDIM / 4) + tid];
                    acc.x += h.x; acc.y += h.y; acc.z += h.z; acc.w += h.w;
                }
            }
            __syncthreads();
        }
        float s = 1.0f / (float)(count > 0 ? count : 1);
        ushort4 o;
        o.x = f2bf(acc.x * s); o.y = f2bf(acc.y * s);
        o.z = f2bf(acc.z * s); o.w = f2bf(acc.w * s);
        *(ushort4*)(Pb + swz_off(row, tid * 4)) = o;   // slot-uniform 8B write
    } else {
        // W[K][N] fp32 -> Wt[N][K] bf16, swizzle-baked. 512 blocks: 16(k) x 16(n) x 2
        int b2 = bid - 8192;
        const float* W = (b2 >> 8) ? W2 : W1;
        char* Wt = (b2 >> 8) ? W2t : W1t;
        int r2 = b2 & 255;
        int k0 = (r2 & 15) * 64, n0 = (r2 >> 4) * 64;
        __shared__ ushort t[64][65];
        #pragma unroll
        for (int it = 0; it < 16; ++it) {
            int idx = it * 256 + tid;
            int r = idx >> 6, c = idx & 63;
            t[c][r] = f2bf(W[(size_t)(k0 + r) * DDIM + n0 + c]);
        }
        __syncthreads();
        #pragma unroll
        for (int it = 0; it < 4; ++it) {   // ushort4 writes: 4 k-consecutive share a slot
            int idx = it * 256 + tid;
            int r = idx >> 4, g = idx & 15;
            ushort4 v;
            v.x = t[r][g * 4]; v.y = t[r][g * 4 + 1];
            v.z = t[r][g * 4 + 2]; v.w = t[r][g * 4 + 3];
            *(ushort4*)(Wt + swz_off(n0 + r, k0 + g * 4)) = v;
        }
    }
}

// ---------------- Kernel 2: out = H@W1 + P@W2 + (b1+b2), 32x32x16 bf16 MFMA -------
// Tile 256(M)x128(N), BK=64, 8 waves (4Mx2N), wave tile 64x64 = 2x2 frags.
// Grid 256 = 1 block/CU (full chip), 2 waves/SIMD. Double-buffered LDS (96KB).
// Issue-early pipeline: ALL staging for t+1 issued before t's MFMA cluster, so the
// single end-of-iter vmcnt(0)+barrier drains loads issued ~1000 cycles earlier.
__global__ __launch_bounds__(512, 2) void gemm_bf16(
    const float* __restrict__ H,      // [8192][1024] fp32 (converted in-flight)
    const char* __restrict__ Pb,      // [8192][1024] bf16, swizzle-baked
    const char* __restrict__ W1t,     // [1024 n][1024 k] bf16, swizzle-baked
    const char* __restrict__ W2t,
    const float* __restrict__ b1,
    const float* __restrict__ b2,
    float* __restrict__ out)          // [8192][1024] fp32
{
    __shared__ __align__(128) char AsBuf[2][32768];   // [256 rows][128B]
    __shared__ __align__(128) char BsBuf[2][16384];   // [128 rows][128B]

    const int tid = threadIdx.x;      // 0..511
    const int lane = tid & 63;
    const int wid = tid >> 6;         // 0..7
    const int wr = wid >> 1, wc = wid & 1;
    const int l31 = lane & 31;
    const int hi2 = lane >> 5;
    const int x7 = l31 & 7;

    // N-tile = bid&7 -> XCD-locality for the W panels (8 N-tiles = 8 XCDs)
    const int bid = blockIdx.x;
    const int row0 = (bid >> 3) * 256;
    const int col0 = (bid & 7) * 128;

    f32x16 acc[2][2];
    #pragma unroll
    for (int mm = 0; mm < 2; ++mm)
        #pragma unroll
        for (int nn = 0; nn < 2; ++nn)
            #pragma unroll
            for (int q = 0; q < 16; ++q) acc[mm][nn][q] = 0.f;

    // staging geometry: one 8KB gload_lds chunk = 64 rows; lane's 16B at
    // o = wid*1024 + lane*16 -> row o>>7, in-row byte o&127
    const int o_lin = wid * 1024 + lane * 16;
    const int srow = o_lin >> 7;
    const int sbyte = o_lin & 127;

    // H reg-stage: thread owns row tid>>1, 64B half tid&1 of the 128B LDS row
    const int hrow = tid >> 1;
    const int hhalf = tid & 1;
    const float* Hrow = H + (size_t)(row0 + hrow) * DDIM + hhalf * 32;
    const int hx = hrow & 7;

    char* Acur = &AsBuf[0][0]; char* Anxt = &AsBuf[1][0];
    char* Bcur = &BsBuf[0][0]; char* Bnxt = &BsBuf[1][0];

    auto stageB = [&](char* dstB, const char* W, int kb) {
        #pragma unroll
        for (int c = 0; c < 2; ++c)
            stage16(W + (size_t)(col0 + c * 64 + srow) * 2048 + kb + sbyte,
                    dstB + c * 8192 + wid * 1024);
    };
    auto stageA_pb = [&](char* dstA, int kb) {
        #pragma unroll
        for (int c = 0; c < 4; ++c)
            stage16(Pb + (size_t)(row0 + c * 64 + srow) * 2048 + kb + sbyte,
                    dstA + c * 8192 + wid * 1024);
    };
    auto writeH = [&](char* dstA, const float4* hv) {
        #pragma unroll
        for (int j = 0; j < 4; ++j) {
            union { ushort u[8]; int4 v; } p;
            float4 a = hv[2 * j], b = hv[2 * j + 1];
            p.u[0] = f2bf(a.x); p.u[1] = f2bf(a.y); p.u[2] = f2bf(a.z); p.u[3] = f2bf(a.w);
            p.u[4] = f2bf(b.x); p.u[5] = f2bf(b.y); p.u[6] = f2bf(b.z); p.u[7] = f2bf(b.w);
            int slot = (hhalf * 4 + j) ^ hx;
            *(int4*)(dstA + hrow * 128 + slot * 16) = p.v;   // swizzle baked at write
        }
    };

    // ---- prologue: stage K-step 0 (H path) into buffer 0 ----
    {
        stageB(Bcur, W1t, 0);
        float4 hv0[8];
        #pragma unroll
        for (int j = 0; j < 8; ++j) hv0[j] = *(const float4*)(Hrow + j * 4);
        writeH(Acur, hv0);
    }
    asm volatile("s_waitcnt vmcnt(0) lgkmcnt(0)" ::: "memory");
    __builtin_amdgcn_s_barrier();

    #pragma unroll 1
    for (int t = 0; t < 32; ++t) {
        const int nxt = t + 1;
        float4 hv[8];
        if (nxt < 16) {
            // H-path prefetch: reg loads first, then B gloads (vmcnt ordering)
            const float* hs = Hrow + nxt * 64;
            #pragma unroll
            for (int j = 0; j < 8; ++j) hv[j] = *(const float4*)(hs + j * 4);
            stageB(Bnxt, W1t, nxt << 7);
        } else if (nxt < 32) {
            int kb = (nxt - 16) << 7;
            stageA_pb(Anxt, kb);
            stageB(Bnxt, W2t, kb);
        }

        // ---- compute K-step t from (Acur, Bcur) ----
        bf16x8 af[2][4], bf[2][4];
        #pragma unroll
        for (int ks = 0; ks < 4; ++ks) {
            const int so = ((ks * 2 + hi2) ^ x7) << 4;
            #pragma unroll
            for (int mm = 0; mm < 2; ++mm)
                af[mm][ks] = *(const bf16x8*)(Acur + (wr * 64 + mm * 32 + l31) * 128 + so);
            #pragma unroll
            for (int nn = 0; nn < 2; ++nn)
                bf[nn][ks] = *(const bf16x8*)(Bcur + (wc * 64 + nn * 32 + l31) * 128 + so);
        }
        __builtin_amdgcn_s_setprio(1);
        #pragma unroll
        for (int ks = 0; ks < 4; ++ks)
            #pragma unroll
            for (int mm = 0; mm < 2; ++mm)
                #pragma unroll
                for (int nn = 0; nn < 2; ++nn)
                    acc[mm][nn] = __builtin_amdgcn_mfma_f32_32x32x16_bf16(
                        af[mm][ks], bf[nn][ks], acc[mm][nn], 0, 0, 0);
        __builtin_amdgcn_s_setprio(0);

        if (nxt < 16) writeH(Anxt, hv);   // convert + swizzled ds_write after MFMA

        // loads for t+1 were issued ~full MFMA cluster ago -> this drain is cheap
        asm volatile("s_waitcnt vmcnt(0) lgkmcnt(0)" ::: "memory");
        __builtin_amdgcn_s_barrier();
        char* tp;
        tp = Acur; Acur = Anxt; Anxt = tp;
        tp = Bcur; Bcur = Bnxt; Bnxt = tp;
    }

    // epilogue: 32x32 C/D layout col=lane&31, row=(reg&3)+8*(reg>>2)+4*(lane>>5)
    #pragma unroll
    for (int mm = 0; mm < 2; ++mm) {
        #pragma unroll
        for (int nn = 0; nn < 2; ++nn) {
            const int c = col0 + wc * 64 + nn * 32 + l31;
            const float bias = b1[c] + b2[c];
            const int rbase = row0 + wr * 64 + mm * 32 + hi2 * 4;
            #pragma unroll
            for (int reg = 0; reg < 16; ++reg) {
                int r = rbase + (reg & 3) + 8 * (reg >> 2);
                out[(size_t)r * DDIM + c] = acc[mm][nn][reg] + bias;
            }
        }
    }
}

extern "C" void kernel_launch(void* const* d_in, const int* in_sizes, int n_in,
                              void* d_out, int out_size, void* d_ws, size_t ws_size,
                              hipStream_t stream) {
    const float* H  = (const float*)d_in[0];
    const int*   ids = (const int*)d_in[1];
    const float* W1 = (const float*)d_in[2];
    const float* b1 = (const float*)d_in[3];
    const float* W2 = (const float*)d_in[4];
    const float* b2 = (const float*)d_in[5];
    float* out = (float*)d_out;

    char* ws = (char*)d_ws;
    char* Pb  = ws;                      // 16MB bf16 pooled (swizzle-baked)
    char* W1t = ws + (16 << 20);         // 2MB
    char* W2t = ws + (18 << 20);         // 2MB  (total 20MB, proven-safe)

    prep<<<8192 + 512, 256, 0, stream>>>(H, ids, W1, W2, Pb, W1t, W2t);
    gemm_bf16<<<256, 512, 0, stream>>>(H, Pb, W1t, W2t, b1, b2, out);
}

// Round 5
// 95.322 us; speedup vs baseline: 1.0578x; 1.0355x over previous
//
#include <hip/hip_runtime.h>
#include <hip/hip_bf16.h>
#include <stdint.h>

// Problem constants: B=4, L=2048, D=1024, vocab<32, N_GRAM=3
#define LSEQ 2048
#define DDIM 1024

typedef __attribute__((ext_vector_type(8))) short bf16x8;
typedef __attribute__((ext_vector_type(16))) float f32x16;

__device__ __forceinline__ ushort f2bf(float x) {
    uint32_t u = __builtin_bit_cast(uint32_t, x);
    u += 0x7fffu + ((u >> 16) & 1u);   // RNE (inputs finite/normal)
    return (ushort)(u >> 16);
}

__device__ __forceinline__ void stage16(const void* g, void* lds) {
    __builtin_amdgcn_global_load_lds((const __attribute__((address_space(1))) void*)g,
                                     (__attribute__((address_space(3))) void*)lds, 16, 0, 0);
}

// Swizzled byte offset in a row-major bf16 buffer, 2048B row stride.
// Within each 128B k-block, 16B slot index XORed with (row&7). Baked into global
// layout by producers (rule 21) so global_load_lds copies linearly; readers XOR.
__device__ __forceinline__ int swz_off(int row, int k) {
    return row * 2048 + ((k >> 6) << 7) + ((((k >> 3) & 7) ^ (row & 7)) << 4) + ((k & 7) << 1);
}

__device__ __forceinline__ int key_at(const int* __restrict__ ids, int base, int j) {
    return j >= 2 ? ((ids[base + j - 2] << 10) | (ids[base + j - 1] << 5) | ids[base + j]) : 0;
}

// ---------------- Kernel 1 (fused prep): pooled (blocks 0..8191) + W-transpose ----
__global__ __launch_bounds__(256) void prep(const float* __restrict__ H,
                                            const int* __restrict__ ids,
                                            const float* __restrict__ W1,
                                            const float* __restrict__ W2,
                                            char* __restrict__ Pb,
                                            char* __restrict__ W1t,
                                            char* __restrict__ W2t) {
    int bid = blockIdx.x;
    int tid = threadIdx.x;
    if (bid < 8192) {
        int row = bid;
        int i = row & (LSEQ - 1);
        int base = row - i;
        int key_i = key_at(ids, base, i);
        const float4* H4 = (const float4*)H;

        __shared__ unsigned bm[8];
        float4 acc = make_float4(0.f, 0.f, 0.f, 0.f);
        int count = 0;
        for (int j0 = 0; j0 < i; j0 += 256) {
            if (tid < 8) bm[tid] = 0u;
            __syncthreads();
            int j = j0 + tid;
            if (j < i && key_at(ids, base, j) == key_i)
                atomicOr(&bm[tid >> 5], 1u << (tid & 31));
            __syncthreads();
            #pragma unroll
            for (int w = 0; w < 8; ++w) {
                unsigned m = bm[w];
                while (m) {
                    int bit = __ffs(m) - 1;
                    m &= m - 1;
                    int j2 = j0 + w * 32 + bit;
                    count++;
                    float4 h = H4[(size_t)(base + j2) * (DDIM / 4) + tid];
                    acc.x += h.x; acc.y += h.y; acc.z += h.z; acc.w += h.w;
                }
            }
            __syncthreads();
        }
        float s = 1.0f / (float)(count > 0 ? count : 1);
        ushort4 o;
        o.x = f2bf(acc.x * s); o.y = f2bf(acc.y * s);
        o.z = f2bf(acc.z * s); o.w = f2bf(acc.w * s);
        *(ushort4*)(Pb + swz_off(row, tid * 4)) = o;
    } else {
        // W[K][N] fp32 -> Wt[N][K] bf16, swizzle-baked. 512 blocks: 16(k) x 16(n) x 2
        int b2 = bid - 8192;
        const float* W = (b2 >> 8) ? W2 : W1;
        char* Wt = (b2 >> 8) ? W2t : W1t;
        int r2 = b2 & 255;
        int k0 = (r2 & 15) * 64, n0 = (r2 >> 4) * 64;
        __shared__ ushort t[64][65];
        #pragma unroll
        for (int it = 0; it < 16; ++it) {
            int idx = it * 256 + tid;
            int r = idx >> 6, c = idx & 63;
            t[c][r] = f2bf(W[(size_t)(k0 + r) * DDIM + n0 + c]);
        }
        __syncthreads();
        #pragma unroll
        for (int it = 0; it < 4; ++it) {
            int idx = it * 256 + tid;
            int r = idx >> 4, g = idx & 15;
            ushort4 v;
            v.x = t[r][g * 4]; v.y = t[r][g * 4 + 1];
            v.z = t[r][g * 4 + 2]; v.w = t[r][g * 4 + 3];
            *(ushort4*)(Wt + swz_off(n0 + r, k0 + g * 4)) = v;
        }
    }
}

// ---------------- Kernel 2: out = H@W1 + P@W2 + (b1+b2), 32x32x16 bf16 MFMA -------
// Tile 256(M)x128(N), BK=64, 8 waves (4Mx2N), wave tile 64x64 = 2x2 frags.
// Grid 256 = 1 block/CU. Triple-buffered LDS (144KB), depth-2 prefetch with
// COUNTED vmcnt (T4): stage(t+2) issued at iter t; per-iter wait vmcnt(10)/(6)
// leaves the newest iteration's loads in flight -> ~2 iters (>2000cy) latency cover.
// XCD swizzle: xcd=bid&7 owns 4 contiguous row-tiles x all 8 col-tiles (H locality).
__global__ __launch_bounds__(512, 2) void gemm_bf16(
    const float* __restrict__ H,      // [8192][1024] fp32 (converted in-flight)
    const char* __restrict__ Pb,      // [8192][1024] bf16, swizzle-baked
    const char* __restrict__ W1t,     // [1024 n][1024 k] bf16, swizzle-baked
    const char* __restrict__ W2t,
    const float* __restrict__ b1,
    const float* __restrict__ b2,
    float* __restrict__ out)          // [8192][1024] fp32
{
    __shared__ __align__(128) char AsBuf[3][32768];   // [256 rows][128B]
    __shared__ __align__(128) char BsBuf[3][16384];   // [128 rows][128B]

    const int tid = threadIdx.x;      // 0..511
    const int lane = tid & 63;
    const int wid = tid >> 6;         // 0..7
    const int wr = wid >> 1, wc = wid & 1;
    const int l31 = lane & 31;
    const int hi2 = lane >> 5;
    const int x7 = l31 & 7;

    // XCD-aware mapping: xcd = bid&7 (round-robin dispatch) -> contiguous rows
    const int bid = blockIdx.x;
    const int j = bid >> 3;                         // 0..31
    const int row0 = ((bid & 7) * 4 + (j >> 3)) * 256;
    const int col0 = (j & 7) * 128;

    f32x16 acc[2][2];
    #pragma unroll
    for (int mm = 0; mm < 2; ++mm)
        #pragma unroll
        for (int nn = 0; nn < 2; ++nn)
            #pragma unroll
            for (int q = 0; q < 16; ++q) acc[mm][nn][q] = 0.f;

    // staging geometry: one 8KB gload_lds chunk = 64 rows
    const int o_lin = wid * 1024 + lane * 16;
    const int srow = o_lin >> 7;
    const int sbyte = o_lin & 127;

    // H reg-stage: thread owns row tid>>1, 64B half tid&1 of the 128B LDS row
    const int hrow = tid >> 1;
    const int hhalf = tid & 1;
    const float* Hrow = H + (size_t)(row0 + hrow) * DDIM + hhalf * 32;
    const int hx = hrow & 7;

    char* Acur = &AsBuf[0][0]; char* Anx1 = &AsBuf[1][0]; char* Anx2 = &AsBuf[2][0];
    char* Bcur = &BsBuf[0][0]; char* Bnx1 = &BsBuf[1][0]; char* Bnx2 = &BsBuf[2][0];

    auto stageB = [&](char* dstB, const char* W, int kb) {
        #pragma unroll
        for (int c = 0; c < 2; ++c)
            stage16(W + (size_t)(col0 + c * 64 + srow) * 2048 + kb + sbyte,
                    dstB + c * 8192 + wid * 1024);
    };
    auto stageA_pb = [&](char* dstA, int kb) {
        #pragma unroll
        for (int c = 0; c < 4; ++c)
            stage16(Pb + (size_t)(row0 + c * 64 + srow) * 2048 + kb + sbyte,
                    dstA + c * 8192 + wid * 1024);
    };
    auto loadH = [&](float4* hv, int t) {
        const float* hs = Hrow + t * 64;
        #pragma unroll
        for (int q = 0; q < 8; ++q) hv[q] = *(const float4*)(hs + q * 4);
    };
    auto writeH = [&](char* dstA, const float4* hv) {
        #pragma unroll
        for (int q = 0; q < 4; ++q) {
            union { ushort u[8]; int4 v; } p;
            float4 a = hv[2 * q], b = hv[2 * q + 1];
            p.u[0] = f2bf(a.x); p.u[1] = f2bf(a.y); p.u[2] = f2bf(a.z); p.u[3] = f2bf(a.w);
            p.u[4] = f2bf(b.x); p.u[5] = f2bf(b.y); p.u[6] = f2bf(b.z); p.u[7] = f2bf(b.w);
            int slot = (hhalf * 4 + q) ^ hx;
            *(int4*)(dstA + hrow * 128 + slot * 16) = p.v;
        }
    };
    auto compute = [&]() {
        bf16x8 af[2][4], bf[2][4];
        #pragma unroll
        for (int ks = 0; ks < 4; ++ks) {
            const int so = ((ks * 2 + hi2) ^ x7) << 4;
            #pragma unroll
            for (int mm = 0; mm < 2; ++mm)
                af[mm][ks] = *(const bf16x8*)(Acur + (wr * 64 + mm * 32 + l31) * 128 + so);
            #pragma unroll
            for (int nn = 0; nn < 2; ++nn)
                bf[nn][ks] = *(const bf16x8*)(Bcur + (wc * 64 + nn * 32 + l31) * 128 + so);
        }
        __builtin_amdgcn_s_setprio(1);
        #pragma unroll
        for (int ks = 0; ks < 4; ++ks)
            #pragma unroll
            for (int mm = 0; mm < 2; ++mm)
                #pragma unroll
                for (int nn = 0; nn < 2; ++nn)
                    acc[mm][nn] = __builtin_amdgcn_mfma_f32_32x32x16_bf16(
                        af[mm][ks], bf[nn][ks], acc[mm][nn], 0, 0, 0);
        __builtin_amdgcn_s_setprio(0);
    };
    auto rotate = [&]() {
        char* tp;
        tp = Acur; Acur = Anx1; Anx1 = Anx2; Anx2 = tp;
        tp = Bcur; Bcur = Bnx1; Bnx1 = Bnx2; Bnx2 = tp;
    };

    float4 hvA[8], hvB[8];

    // ---- prologue: stage steps 0 and 1 ----
    stageB(Bcur, W1t, 0);        loadH(hvA, 0);     // batch0: 10 VMEM
    stageB(Bnx1, W1t, 1 << 7);   loadH(hvB, 1);     // batch1: 10 VMEM
    asm volatile("s_waitcnt vmcnt(10)" ::: "memory");   // batch0 done
    writeH(Acur, hvA);
    asm volatile("s_waitcnt lgkmcnt(0)" ::: "memory");
    __builtin_amdgcn_s_barrier();

    // ---- H-path iters 0..13 (consume t; issue t+2; write hv(t+1)) ----
    #pragma unroll 1
    for (int t = 0; t < 14; t += 2) {
        // even iter: wr=hvB (holds hv(t+1)), ld=hvA (gets hv(t+2))
        stageB(Bnx2, W1t, (t + 2) << 7);
        loadH(hvA, t + 2);
        compute();
        asm volatile("s_waitcnt vmcnt(10)" ::: "memory");   // t+1's loads done
        writeH(Anx1, hvB);
        asm volatile("s_waitcnt lgkmcnt(0)" ::: "memory");
        __builtin_amdgcn_s_barrier();
        rotate();
        // odd iter: wr=hvA, ld=hvB
        stageB(Bnx2, W1t, (t + 3) << 7);
        loadH(hvB, t + 3);
        compute();
        asm volatile("s_waitcnt vmcnt(10)" ::: "memory");
        writeH(Anx1, hvA);
        asm volatile("s_waitcnt lgkmcnt(0)" ::: "memory");
        __builtin_amdgcn_s_barrier();
        rotate();
    }

    // ---- iter 14: consume buf14; issue P-step 16; write hv(15) ----
    stageA_pb(Anx2, 0); stageB(Bnx2, W2t, 0);
    compute();
    asm volatile("s_waitcnt vmcnt(6)" ::: "memory");        // hv(15)+B(15) done
    writeH(Anx1, hvB);
    asm volatile("s_waitcnt lgkmcnt(0)" ::: "memory");
    __builtin_amdgcn_s_barrier();
    rotate();

    // ---- iter 15: consume buf15; issue P-step 17 ----
    stageA_pb(Anx2, 1 << 7); stageB(Bnx2, W2t, 1 << 7);
    compute();
    asm volatile("s_waitcnt vmcnt(6)" ::: "memory");        // step-16 stage done
    __builtin_amdgcn_s_barrier();
    rotate();

    // ---- P-path iters 16..29 ----
    #pragma unroll 1
    for (int t = 16; t < 30; ++t) {
        int kb = (t - 14) << 7;
        stageA_pb(Anx2, kb); stageB(Bnx2, W2t, kb);
        compute();
        asm volatile("s_waitcnt vmcnt(6)" ::: "memory");
        __builtin_amdgcn_s_barrier();
        rotate();
    }

    // ---- iter 30: nothing to issue; drain step-31 stage ----
    compute();
    asm volatile("s_waitcnt vmcnt(0)" ::: "memory");
    __builtin_amdgcn_s_barrier();
    rotate();

    // ---- iter 31 ----
    compute();

    // epilogue: 32x32 C/D layout col=lane&31, row=(reg&3)+8*(reg>>2)+4*(lane>>5)
    #pragma unroll
    for (int mm = 0; mm < 2; ++mm) {
        #pragma unroll
        for (int nn = 0; nn < 2; ++nn) {
            const int c = col0 + wc * 64 + nn * 32 + l31;
            const float bias = b1[c] + b2[c];
            const int rbase = row0 + wr * 64 + mm * 32 + hi2 * 4;
            #pragma unroll
            for (int reg = 0; reg < 16; ++reg) {
                int r = rbase + (reg & 3) + 8 * (reg >> 2);
                out[(size_t)r * DDIM + c] = acc[mm][nn][reg] + bias;
            }
        }
    }
}

extern "C" void kernel_launch(void* const* d_in, const int* in_sizes, int n_in,
                              void* d_out, int out_size, void* d_ws, size_t ws_size,
                              hipStream_t stream) {
    const float* H  = (const float*)d_in[0];
    const int*   ids = (const int*)d_in[1];
    const float* W1 = (const float*)d_in[2];
    const float* b1 = (const float*)d_in[3];
    const float* W2 = (const float*)d_in[4];
    const float* b2 = (const float*)d_in[5];
    float* out = (float*)d_out;

    char* ws = (char*)d_ws;
    char* Pb  = ws;                      // 16MB bf16 pooled (swizzle-baked)
    char* W1t = ws + (16 << 20);         // 2MB
    char* W2t = ws + (18 << 20);         // 2MB  (total 20MB, proven-safe)

    prep<<<8192 + 512, 256, 0, stream>>>(H, ids, W1, W2, Pb, W1t, W2t);
    gemm_bf16<<<256, 512, 0, stream>>>(H, Pb, W1t, W2t, b1, b2, out);
}